// Round 3
// baseline (703.826 us; speedup 1.0000x reference)
//
#include <hip/hip_runtime.h>
#include <math.h>

#define F 128
#define HEADS 8

typedef __attribute__((ext_vector_type(8))) short short8;
typedef __attribute__((ext_vector_type(4))) float floatx4;
typedef __attribute__((ext_vector_type(2))) _Float16 half2v;

__device__ __forceinline__ unsigned short f2bf(float f) {
    unsigned u = __float_as_uint(f);
    unsigned r = u + 0x7FFFu + ((u >> 16) & 1u);
    return (unsigned short)(r >> 16);
}

__device__ __forceinline__ half2v ashalf2(unsigned u) {
    return __builtin_bit_cast(half2v, u);
}
__device__ __forceinline__ unsigned pkh(float a, float b) {
    return __builtin_bit_cast(unsigned, __builtin_amdgcn_cvt_pkrtz(a, b));
}

#if __has_builtin(__builtin_amdgcn_fdot2)
#define FDOT2(a, b, c) __builtin_amdgcn_fdot2((a), (b), (c), false)
#else
#define FDOT2(a, b, c) ((c) + (float)(a)[0] * (float)(b)[0] + (float)(a)[1] * (float)(b)[1])
#endif

// ---------------- CSR build ----------------

__global__ __launch_bounds__(256) void hist_k(const int* __restrict__ dst, int E, int* __restrict__ deg) {
    int e = blockIdx.x * 256 + threadIdx.x;
    if (e < E) atomicAdd(&deg[dst[e]], 1);
}

__global__ __launch_bounds__(256) void scan1_k(const int* __restrict__ deg, int N,
                                               int* __restrict__ start, int* __restrict__ partials) {
    __shared__ int sm[256];
    int t = threadIdx.x;
    int i = blockIdx.x * 256 + t;
    int v = (i < N) ? deg[i] : 0;
    sm[t] = v;
    __syncthreads();
    for (int off = 1; off < 256; off <<= 1) {
        int add = (t >= off) ? sm[t - off] : 0;
        __syncthreads();
        sm[t] += add;
        __syncthreads();
    }
    if (i < N) start[i] = sm[t] - v;
    if (t == 255) partials[blockIdx.x] = sm[t];
}

__global__ __launch_bounds__(256) void scan2_k(int* __restrict__ partials, int nb,
                                               int* __restrict__ start, int N, int E) {
    __shared__ int sm[256];
    int t = threadIdx.x;
    int v = (t < nb) ? partials[t] : 0;
    sm[t] = v;
    __syncthreads();
    for (int off = 1; off < 256; off <<= 1) {
        int add = (t >= off) ? sm[t - off] : 0;
        __syncthreads();
        sm[t] += add;
        __syncthreads();
    }
    if (t < nb) partials[t] = sm[t] - v;
    if (t == 0) start[N] = E;
}

__global__ __launch_bounds__(256) void scan3_k(int* __restrict__ start, int N, const int* __restrict__ partials) {
    int i = blockIdx.x * 256 + threadIdx.x;
    if (i < N) start[i] += partials[blockIdx.x];
}

// epair[i] = (edge_id, src)
__global__ __launch_bounds__(256) void fill_k(const int* __restrict__ src, const int* __restrict__ dst, int E,
                                              const int* __restrict__ start, int* __restrict__ cursor,
                                              int2* __restrict__ epair) {
    int e = blockIdx.x * 256 + threadIdx.x;
    if (e < E) {
        int dd = dst[e];
        int pos = atomicAdd(&cursor[dd], 1);
        epair[start[dd] + pos] = make_int2(e, src[e]);
    }
}

// ---------------- x -> bf16 ----------------
__global__ __launch_bounds__(256) void cvt_k(const float* __restrict__ x, unsigned short* __restrict__ xb, int total4) {
    int i = blockIdx.x * 256 + threadIdx.x;
    if (i < total4) {
        float4 v = ((const float4*)x)[i];
        ushort4 o;
        o.x = f2bf(v.x); o.y = f2bf(v.y); o.z = f2bf(v.z); o.w = f2bf(v.w);
        ((ushort4*)xb)[i] = o;
    }
}

// ---------------- weight pre-swizzle: fp32 W -> bf16 MFMA A-fragments ----------------

__global__ __launch_bounds__(256) void wprep_k(
    const float* __restrict__ Wq, const float* __restrict__ Wk,
    const float* __restrict__ Wv, const float* __restrict__ Ws,
    unsigned short* __restrict__ out, int total) {
    int idx = blockIdx.x * 256 + threadIdx.x;
    if (idx >= total) return;
    int j = idx & 7;
    int lane = (idx >> 3) & 63;
    int rest = idx >> 9;
    int chunk = rest & 3;
    int ftile = (rest >> 2) & 7;
    int mat = (rest >> 5) & 3;
    int layer = rest >> 7;
    int k = chunk * 32 + (lane >> 4) * 8 + j;
    int f = ftile * 16 + (lane & 15);
    const float* W = (mat == 0) ? Wq : (mat == 1) ? Wk : (mat == 2) ? Wv : Ws;
    out[idx] = f2bf(W[((size_t)layer * F + k) * F + f]);
}

// ---------------- fused QKVS GEMM via bf16 MFMA ----------------
// wave 0:Q(f16) 1:K(f16) 2:V(f16) 3:S(f32) for 32 nodes each.

__global__ __launch_bounds__(256) void gemm_mfma(
    const unsigned short* __restrict__ xb, const unsigned short* __restrict__ wfrag,
    const float* __restrict__ bq, const float* __restrict__ bk,
    const float* __restrict__ bv, const float* __restrict__ bs,
    unsigned short* __restrict__ Qh, unsigned short* __restrict__ Kh,
    unsigned short* __restrict__ Vh, float* __restrict__ S, int N) {
    int wave = threadIdx.x >> 6;
    int lane = threadIdx.x & 63;
    int row0 = blockIdx.x * 32;
    int lm = lane & 15, quad = lane >> 4;
    const unsigned short* wf = wfrag + wave * 16384;

    floatx4 acc[2][8];
#pragma unroll
    for (int t = 0; t < 2; t++)
#pragma unroll
        for (int u = 0; u < 8; u++) acc[t][u] = (floatx4){0.f, 0.f, 0.f, 0.f};

#pragma unroll
    for (int chunk = 0; chunk < 4; chunk++) {
        short8 xfr[2];
#pragma unroll
        for (int t = 0; t < 2; t++) {
            int m = row0 + t * 16 + lm;
            m = (m < N) ? m : (N - 1);
            xfr[t] = *(const short8*)(xb + (size_t)m * F + chunk * 32 + quad * 8);
        }
#pragma unroll
        for (int u = 0; u < 8; u++) {
            short8 wfr = *(const short8*)(wf + ((u * 4 + chunk) * 64 + lane) * 8);
            acc[0][u] = __builtin_amdgcn_mfma_f32_16x16x32_bf16(wfr, xfr[0], acc[0][u], 0, 0, 0);
            acc[1][u] = __builtin_amdgcn_mfma_f32_16x16x32_bf16(wfr, xfr[1], acc[1][u], 0, 0, 0);
        }
    }

    const float* bias = (wave == 0) ? bq : (wave == 1) ? bk : (wave == 2) ? bv : bs;
#pragma unroll
    for (int u = 0; u < 8; u++) {
        float4 bv4 = *(const float4*)&bias[u * 16 + quad * 4];
#pragma unroll
        for (int t = 0; t < 2; t++) {
            int node = row0 + t * 16 + lm;
            if (node < N) {
                floatx4 a = acc[t][u];
                size_t off = (size_t)node * F + u * 16 + quad * 4;
                float v0 = a[0] + bv4.x, v1 = a[1] + bv4.y, v2 = a[2] + bv4.z, v3 = a[3] + bv4.w;
                if (wave == 3) {
                    *(float4*)&S[off] = make_float4(v0, v1, v2, v3);
                } else {
                    unsigned short* dp = (wave == 0) ? Qh : (wave == 1) ? Kh : Vh;
                    *(uint2*)&dp[off] = make_uint2(pkh(v0, v1), pkh(v2, v3));
                }
            }
        }
    }
}

// ---------------- fused edge kernel: one wave per destination node ----------------
// Per 64-edge chunk: ONE coalesced epair load into lane registers; src/eid
// distributed by __shfl. Phase-2 head V loads issued BEFORE phase 1 (latency
// hidden under QK dots). Phase 1 and phase 2 both software-pipelined with
// clamped-valid unconditional prefetches.

__device__ __forceinline__ float gelu_exact(float v) {
    return 0.5f * v * (1.0f + erff(v * 0.70710678118654752f));
}

__global__ __launch_bounds__(256) void edge_k(
    const unsigned short* __restrict__ Qh, const unsigned short* __restrict__ Kh,
    const unsigned short* __restrict__ Vh, const float* __restrict__ S,
    const int* __restrict__ start, const int2* __restrict__ epair,
    float* __restrict__ aout,
    float* __restrict__ hout_f, unsigned short* __restrict__ hout_b,
    int N, int do_gelu) {
    __shared__ float wbuf[4][64][8];
    __shared__ float mdbuf[4][8];

    int wv = threadIdx.x >> 6;
    int lane = threadIdx.x & 63;
    int n = blockIdx.x * 4 + wv;
    if (n >= N) return;   // no block-level barriers below: safe

    int beg = start[n], end = start[n + 1];
    int deg = end - beg;
    bool multi = deg > 64;
    int slot = lane >> 3, h = lane & 7;
    int g = lane >> 4, fl = lane & 15;
    int fh = fl >> 1;

    // q for head h: 16 f16
    const unsigned short* qp = Qh + (size_t)n * F + h * 16;
    uint4 qa = *(const uint4*)(qp);
    uint4 qc = *(const uint4*)(qp + 8);
    half2v q0 = ashalf2(qa.x), q1 = ashalf2(qa.y), q2 = ashalf2(qa.z), q3 = ashalf2(qa.w);
    half2v q4 = ashalf2(qc.x), q5 = ashalf2(qc.y), q6 = ashalf2(qc.z), q7 = ashalf2(qc.w);

    float d = 0.f;
    float a0 = 0.f, a1 = 0.f, a2 = 0.f, a3 = 0.f, a4 = 0.f, a5 = 0.f, a6 = 0.f, a7 = 0.f;
    int2 peL = make_int2(0, 0);

    for (int c0 = beg; c0 < end; c0 += 64) {
        int cnt = min(64, end - c0);

        // one coalesced load covers the whole chunk's (edge_id, src) pairs
        int2 pe = epair[c0 + min(lane, cnt - 1)];
        peL = pe;

        // ---- issue phase-2 head V loads now (hide under phase 1) ----
        int s0 = __shfl(pe.y, g, 64);
        int s1 = __shfl(pe.y, 4 + g, 64);
        uint4 va = *(const uint4*)&Vh[(size_t)s0 * F + fl * 8];
        uint4 vb2 = *(const uint4*)&Vh[(size_t)s1 * F + fl * 8];

        // ---- phase 1: alpha / w (pipelined) ----
        int nit = (cnt + 7) >> 3;
        int idx = slot;
        int s = __shfl(pe.y, idx, 64);
        const unsigned short* kp = Kh + (size_t)s * F + h * 16;
        uint4 ka = *(const uint4*)kp;
        uint4 kc = *(const uint4*)(kp + 8);
        for (int it = 0; it < nit; it++) {
            int nidx = idx + 8;
            int ns = __shfl(pe.y, min(nidx, 63), 64);
            const unsigned short* nkp = Kh + (size_t)ns * F + h * 16;
            uint4 nka = *(const uint4*)nkp;          // clamped-valid prefetch
            uint4 nkc = *(const uint4*)(nkp + 8);
            bool val = idx < cnt;
            float p0 = 0.f, p1 = 0.f;
            p0 = FDOT2(q0, ashalf2(ka.x), p0);
            p0 = FDOT2(q1, ashalf2(ka.y), p0);
            p0 = FDOT2(q2, ashalf2(ka.z), p0);
            p0 = FDOT2(q3, ashalf2(ka.w), p0);
            p1 = FDOT2(q4, ashalf2(kc.x), p1);
            p1 = FDOT2(q5, ashalf2(kc.y), p1);
            p1 = FDOT2(q6, ashalf2(kc.z), p1);
            p1 = FDOT2(q7, ashalf2(kc.w), p1);
            float w = __expf((p0 + p1) * 0.25f);  // 1/sqrt(16)
            if (!val) w = 0.f;
            d += w;
            wbuf[wv][idx][h] = w;
            if (multi) {                           // rare fallback: unnormalized write
                int eid = __shfl(pe.x, idx, 64);
                if (val) aout[(size_t)eid * HEADS + h] = w;
            }
            ka = nka; kc = nkc; idx = nidx;
        }

        // ---- phase 2: V accumulation (pipelined) ----
        for (int j = 0; j < cnt; j += 8) {
            int ns0 = __shfl(pe.y, min(j + 8 + g, 63), 64);
            int ns1 = __shfl(pe.y, min(j + 12 + g, 63), 64);
            uint4 na = *(const uint4*)&Vh[(size_t)ns0 * F + fl * 8];   // prefetch
            uint4 nb = *(const uint4*)&Vh[(size_t)ns1 * F + fl * 8];
            bool v0 = (j + g) < cnt;
            bool v1 = (j + 4 + g) < cnt;
            float w0 = v0 ? wbuf[wv][j + g][fh] : 0.f;
            float w1 = v1 ? wbuf[wv][j + 4 + g][fh] : 0.f;
            half2v x0 = ashalf2(va.x), x1 = ashalf2(va.y), x2 = ashalf2(va.z), x3 = ashalf2(va.w);
            half2v y0 = ashalf2(vb2.x), y1 = ashalf2(vb2.y), y2 = ashalf2(vb2.z), y3 = ashalf2(vb2.w);
            a0 += w0 * (float)x0[0]; a1 += w0 * (float)x0[1];
            a2 += w0 * (float)x1[0]; a3 += w0 * (float)x1[1];
            a4 += w0 * (float)x2[0]; a5 += w0 * (float)x2[1];
            a6 += w0 * (float)x3[0]; a7 += w0 * (float)x3[1];
            a0 += w1 * (float)y0[0]; a1 += w1 * (float)y0[1];
            a2 += w1 * (float)y1[0]; a3 += w1 * (float)y1[1];
            a4 += w1 * (float)y2[0]; a5 += w1 * (float)y2[1];
            a6 += w1 * (float)y3[0]; a7 += w1 * (float)y3[1];
            va = na; vb2 = nb;
        }
    }

    // reduce d over slots (lanes sharing h)
    d += __shfl_xor(d, 8);
    d += __shfl_xor(d, 16);
    d += __shfl_xor(d, 32);
    float inv_d = (d > 0.f) ? 1.f / d : 0.f;
    if (slot == 0) mdbuf[wv][h] = inv_d;

    // ---- fused alpha normalization ----
    if (!multi) {
        // all w's still in wbuf; eids in peL registers (single chunk)
        for (int base = 0; base < deg; base += 8) {
            int idx = base + slot;
            int eid = __shfl(peL.x, min(idx, 63), 64);
            if (idx < deg) aout[(size_t)eid * HEADS + h] = wbuf[wv][idx][h] * inv_d;
        }
    } else {
        // rare: rescale the unnormalized values written in phase 1 (same-lane RMW)
        for (int idx = slot; idx < deg; idx += 8)
            aout[(size_t)epair[beg + idx].x * HEADS + h] *= inv_d;
    }

    // combine the 4 phase-2 groups
    a0 += __shfl_xor(a0, 16); a0 += __shfl_xor(a0, 32);
    a1 += __shfl_xor(a1, 16); a1 += __shfl_xor(a1, 32);
    a2 += __shfl_xor(a2, 16); a2 += __shfl_xor(a2, 32);
    a3 += __shfl_xor(a3, 16); a3 += __shfl_xor(a3, 32);
    a4 += __shfl_xor(a4, 16); a4 += __shfl_xor(a4, 32);
    a5 += __shfl_xor(a5, 16); a5 += __shfl_xor(a5, 32);
    a6 += __shfl_xor(a6, 16); a6 += __shfl_xor(a6, 32);
    a7 += __shfl_xor(a7, 16); a7 += __shfl_xor(a7, 32);

    if (lane < 16) {
        float invd = mdbuf[wv][fh];
        const float* sp = S + (size_t)n * F + fl * 8;
        float4 s0v = *(const float4*)(sp + 0);
        float4 s1v = *(const float4*)(sp + 4);
        float o0 = a0 * invd + s0v.x, o1 = a1 * invd + s0v.y;
        float o2 = a2 * invd + s0v.z, o3 = a3 * invd + s0v.w;
        float o4 = a4 * invd + s1v.x, o5 = a5 * invd + s1v.y;
        float o6 = a6 * invd + s1v.z, o7 = a7 * invd + s1v.w;
        if (do_gelu) {
            o0 = gelu_exact(o0); o1 = gelu_exact(o1); o2 = gelu_exact(o2); o3 = gelu_exact(o3);
            o4 = gelu_exact(o4); o5 = gelu_exact(o5); o6 = gelu_exact(o6); o7 = gelu_exact(o7);
            uint4 ob;
            ob.x = (unsigned)f2bf(o0) | ((unsigned)f2bf(o1) << 16);
            ob.y = (unsigned)f2bf(o2) | ((unsigned)f2bf(o3) << 16);
            ob.z = (unsigned)f2bf(o4) | ((unsigned)f2bf(o5) << 16);
            ob.w = (unsigned)f2bf(o6) | ((unsigned)f2bf(o7) << 16);
            *(uint4*)&hout_b[(size_t)n * F + fl * 8] = ob;
        } else {
            float* op = hout_f + (size_t)n * F + fl * 8;
            *(float4*)(op + 0) = make_float4(o0, o1, o2, o3);
            *(float4*)(op + 4) = make_float4(o4, o5, o6, o7);
        }
    }
}

// ---------------- launch ----------------

extern "C" void kernel_launch(void* const* d_in, const int* in_sizes, int n_in,
                              void* d_out, int out_size, void* d_ws, size_t ws_size,
                              hipStream_t stream) {
    const float* x  = (const float*)d_in[0];
    const int*   ei = (const int*)d_in[1];
    const float* Wq = (const float*)d_in[2];
    const float* bq = (const float*)d_in[3];
    const float* Wk = (const float*)d_in[4];
    const float* bk = (const float*)d_in[5];
    const float* Wv = (const float*)d_in[6];
    const float* bv = (const float*)d_in[7];
    const float* Ws = (const float*)d_in[8];
    const float* bs = (const float*)d_in[9];

    const int N = in_sizes[0] / F;
    const int E = in_sizes[1] / 2;
    const int L = in_sizes[2] / (F * F);

    // workspace layout
    float* Sb = (float*)d_ws;                             // N*F fp32
    unsigned short* Qh = (unsigned short*)(Sb + (size_t)N * F);  // N*F f16
    unsigned short* xb = Qh + (size_t)N * F;              // N*F bf16
    unsigned short* hb = xb + (size_t)N * F;              // N*F bf16
    unsigned short* Kb = hb + (size_t)N * F;              // N*F f16
    unsigned short* Vb = Kb + (size_t)N * F;              // N*F f16
    unsigned short* wfrag = Vb + (size_t)N * F;           // L*4*16384 bf16
    int2* epair = (int2*)(wfrag + (size_t)L * 4 * 16384); // E int2 (8B aligned)
    int* start = (int*)(epair + E);                       // N+1
    int* cursor = start + (N + 1);                        // N
    int* partials = cursor + N;                           // <=256

    float* out_h = (float*)d_out;                         // N*F
    float* out_a = out_h + (size_t)N * F;                 // L*E*HEADS

    const int* srcIdx = ei;
    const int* dstIdx = ei + E;

    int nbScan = (N + 255) / 256;
    hipMemsetAsync(cursor, 0, sizeof(int) * N, stream);
    hist_k<<<(E + 255) / 256, 256, 0, stream>>>(dstIdx, E, cursor);
    scan1_k<<<nbScan, 256, 0, stream>>>(cursor, N, start, partials);
    scan2_k<<<1, 256, 0, stream>>>(partials, nbScan, start, N, E);
    scan3_k<<<nbScan, 256, 0, stream>>>(start, N, partials);
    hipMemsetAsync(cursor, 0, sizeof(int) * N, stream);
    fill_k<<<(E + 255) / 256, 256, 0, stream>>>(srcIdx, dstIdx, E, start, cursor, epair);

    int wtotal = L * 4 * 16384;
    wprep_k<<<(wtotal + 255) / 256, 256, 0, stream>>>(Wq, Wk, Wv, Ws, wfrag, wtotal);
    cvt_k<<<((N * F / 4) + 255) / 256, 256, 0, stream>>>(x, xb, N * F / 4);

    for (int l = 0; l < L; ++l) {
        const unsigned short* hin = (l == 0) ? xb : hb;
        gemm_mfma<<<(N + 31) / 32, 256, 0, stream>>>(
            hin, wfrag + (size_t)l * 4 * 16384,
            bq + (size_t)l * F, bk + (size_t)l * F,
            bv + (size_t)l * F, bs + (size_t)l * F,
            Qh, Kb, Vb, Sb, N);
        edge_k<<<(N + 3) / 4, 256, 0, stream>>>(
            Qh, Kb, Vb, Sb, start, epair,
            out_a + (size_t)l * E * HEADS, out_h, hb, N, (l < L - 1) ? 1 : 0);
    }
}

// Round 4
// 679.647 us; speedup vs baseline: 1.0356x; 1.0356x over previous
//
#include <hip/hip_runtime.h>
#include <math.h>

#define F 128
#define HEADS 8

typedef __attribute__((ext_vector_type(8))) short short8;
typedef __attribute__((ext_vector_type(4))) float floatx4;
typedef __attribute__((ext_vector_type(2))) _Float16 half2v;

__device__ __forceinline__ unsigned short f2bf(float f) {
    unsigned u = __float_as_uint(f);
    unsigned r = u + 0x7FFFu + ((u >> 16) & 1u);
    return (unsigned short)(r >> 16);
}

__device__ __forceinline__ half2v ashalf2(unsigned u) {
    return __builtin_bit_cast(half2v, u);
}
__device__ __forceinline__ unsigned pkh(float a, float b) {
    return __builtin_bit_cast(unsigned, __builtin_amdgcn_cvt_pkrtz(a, b));
}

#if __has_builtin(__builtin_amdgcn_fdot2)
#define FDOT2(a, b, c) __builtin_amdgcn_fdot2((a), (b), (c), false)
#else
#define FDOT2(a, b, c) ((c) + (float)(a)[0] * (float)(b)[0] + (float)(a)[1] * (float)(b)[1])
#endif

// ---------------- CSR build ----------------

__global__ __launch_bounds__(256) void hist_k(const int* __restrict__ dst, int E, int* __restrict__ deg) {
    int e = blockIdx.x * 256 + threadIdx.x;
    if (e < E) atomicAdd(&deg[dst[e]], 1);
}

__global__ __launch_bounds__(256) void scan1_k(const int* __restrict__ deg, int N,
                                               int* __restrict__ start, int* __restrict__ partials) {
    __shared__ int sm[256];
    int t = threadIdx.x;
    int i = blockIdx.x * 256 + t;
    int v = (i < N) ? deg[i] : 0;
    sm[t] = v;
    __syncthreads();
    for (int off = 1; off < 256; off <<= 1) {
        int add = (t >= off) ? sm[t - off] : 0;
        __syncthreads();
        sm[t] += add;
        __syncthreads();
    }
    if (i < N) start[i] = sm[t] - v;
    if (t == 255) partials[blockIdx.x] = sm[t];
}

__global__ __launch_bounds__(256) void scan2_k(int* __restrict__ partials, int nb,
                                               int* __restrict__ start, int N, int E) {
    __shared__ int sm[256];
    int t = threadIdx.x;
    int v = (t < nb) ? partials[t] : 0;
    sm[t] = v;
    __syncthreads();
    for (int off = 1; off < 256; off <<= 1) {
        int add = (t >= off) ? sm[t - off] : 0;
        __syncthreads();
        sm[t] += add;
        __syncthreads();
    }
    if (t < nb) partials[t] = sm[t] - v;
    if (t == 0) start[N] = E;
}

__global__ __launch_bounds__(256) void scan3_k(int* __restrict__ start, int N, const int* __restrict__ partials) {
    int i = blockIdx.x * 256 + threadIdx.x;
    if (i < N) start[i] += partials[blockIdx.x];
}

// epair[i] = (edge_id, src)
__global__ __launch_bounds__(256) void fill_k(const int* __restrict__ src, const int* __restrict__ dst, int E,
                                              const int* __restrict__ start, int* __restrict__ cursor,
                                              int2* __restrict__ epair) {
    int e = blockIdx.x * 256 + threadIdx.x;
    if (e < E) {
        int dd = dst[e];
        int pos = atomicAdd(&cursor[dd], 1);
        epair[start[dd] + pos] = make_int2(e, src[e]);
    }
}

// ---------------- x -> bf16 ----------------
__global__ __launch_bounds__(256) void cvt_k(const float* __restrict__ x, unsigned short* __restrict__ xb, int total4) {
    int i = blockIdx.x * 256 + threadIdx.x;
    if (i < total4) {
        float4 v = ((const float4*)x)[i];
        ushort4 o;
        o.x = f2bf(v.x); o.y = f2bf(v.y); o.z = f2bf(v.z); o.w = f2bf(v.w);
        ((ushort4*)xb)[i] = o;
    }
}

// ---------------- weight pre-swizzle: fp32 W -> bf16 MFMA A-fragments ----------------

__global__ __launch_bounds__(256) void wprep_k(
    const float* __restrict__ Wq, const float* __restrict__ Wk,
    const float* __restrict__ Wv, const float* __restrict__ Ws,
    unsigned short* __restrict__ out, int total) {
    int idx = blockIdx.x * 256 + threadIdx.x;
    if (idx >= total) return;
    int j = idx & 7;
    int lane = (idx >> 3) & 63;
    int rest = idx >> 9;
    int chunk = rest & 3;
    int ftile = (rest >> 2) & 7;
    int mat = (rest >> 5) & 3;
    int layer = rest >> 7;
    int k = chunk * 32 + (lane >> 4) * 8 + j;
    int f = ftile * 16 + (lane & 15);
    const float* W = (mat == 0) ? Wq : (mat == 1) ? Wk : (mat == 2) ? Wv : Ws;
    out[idx] = f2bf(W[((size_t)layer * F + k) * F + f]);
}

// ---------------- fused QKVS GEMM via bf16 MFMA ----------------
// wave 0:Q(f16) 1:K(f16) 2:V(f16) 3:S(f32) for 32 nodes each.

__global__ __launch_bounds__(256) void gemm_mfma(
    const unsigned short* __restrict__ xb, const unsigned short* __restrict__ wfrag,
    const float* __restrict__ bq, const float* __restrict__ bk,
    const float* __restrict__ bv, const float* __restrict__ bs,
    unsigned short* __restrict__ Qh, unsigned short* __restrict__ Kh,
    unsigned short* __restrict__ Vh, float* __restrict__ S, int N) {
    int wave = threadIdx.x >> 6;
    int lane = threadIdx.x & 63;
    int row0 = blockIdx.x * 32;
    int lm = lane & 15, quad = lane >> 4;
    const unsigned short* wf = wfrag + wave * 16384;

    floatx4 acc[2][8];
#pragma unroll
    for (int t = 0; t < 2; t++)
#pragma unroll
        for (int u = 0; u < 8; u++) acc[t][u] = (floatx4){0.f, 0.f, 0.f, 0.f};

#pragma unroll
    for (int chunk = 0; chunk < 4; chunk++) {
        short8 xfr[2];
#pragma unroll
        for (int t = 0; t < 2; t++) {
            int m = row0 + t * 16 + lm;
            m = (m < N) ? m : (N - 1);
            xfr[t] = *(const short8*)(xb + (size_t)m * F + chunk * 32 + quad * 8);
        }
#pragma unroll
        for (int u = 0; u < 8; u++) {
            short8 wfr = *(const short8*)(wf + ((u * 4 + chunk) * 64 + lane) * 8);
            acc[0][u] = __builtin_amdgcn_mfma_f32_16x16x32_bf16(wfr, xfr[0], acc[0][u], 0, 0, 0);
            acc[1][u] = __builtin_amdgcn_mfma_f32_16x16x32_bf16(wfr, xfr[1], acc[1][u], 0, 0, 0);
        }
    }

    const float* bias = (wave == 0) ? bq : (wave == 1) ? bk : (wave == 2) ? bv : bs;
#pragma unroll
    for (int u = 0; u < 8; u++) {
        float4 bv4 = *(const float4*)&bias[u * 16 + quad * 4];
#pragma unroll
        for (int t = 0; t < 2; t++) {
            int node = row0 + t * 16 + lm;
            if (node < N) {
                floatx4 a = acc[t][u];
                size_t off = (size_t)node * F + u * 16 + quad * 4;
                float v0 = a[0] + bv4.x, v1 = a[1] + bv4.y, v2 = a[2] + bv4.z, v3 = a[3] + bv4.w;
                if (wave == 3) {
                    *(float4*)&S[off] = make_float4(v0, v1, v2, v3);
                } else {
                    unsigned short* dp = (wave == 0) ? Qh : (wave == 1) ? Kh : Vh;
                    *(uint2*)&dp[off] = make_uint2(pkh(v0, v1), pkh(v2, v3));
                }
            }
        }
    }
}

// ---------------- fused edge kernel: one wave per destination node ----------------
// Phase 1 (round-1 structure): lane=(slot=lane>>3, h=lane&7): per-lane epair
// load (8-way redundant, cache-broadcast), 16-dim f16 dot via v_dot2.
// Phase 2: lane=(g=lane>>4, fl=lane&15): V rows f16 16B/lane, src/w from LDS.
// Epilogue: group partials exchanged through LDS so ALL 64 lanes do the
// S-add + gelu (2 features/lane) instead of 16 lanes x 8 features.

__device__ __forceinline__ float gelu_exact(float v) {
    return 0.5f * v * (1.0f + erff(v * 0.70710678118654752f));
}

__global__ __launch_bounds__(256) void edge_k(
    const unsigned short* __restrict__ Qh, const unsigned short* __restrict__ Kh,
    const unsigned short* __restrict__ Vh, const float* __restrict__ S,
    const int* __restrict__ start, const int2* __restrict__ epair,
    float* __restrict__ aout,
    float* __restrict__ hout_f, unsigned short* __restrict__ hout_b,
    int N, int do_gelu) {
    __shared__ float wbuf[4][64][8];   // w values, later reused for partials
    __shared__ int sbuf[4][64];
    __shared__ int ebuf[4][64];
    __shared__ float mdbuf[4][8];

    int wv = threadIdx.x >> 6;
    int lane = threadIdx.x & 63;
    int n = blockIdx.x * 4 + wv;
    if (n >= N) return;   // no block-level barriers below: safe

    int beg = start[n], end = start[n + 1];
    int deg = end - beg;
    bool multi = deg > 64;
    int slot = lane >> 3, h = lane & 7;
    int g = lane >> 4, fl = lane & 15;
    int fh = fl >> 1;

    // q for head h: 16 f16
    const unsigned short* qp = Qh + (size_t)n * F + h * 16;
    uint4 qa = *(const uint4*)(qp);
    uint4 qc = *(const uint4*)(qp + 8);
    half2v q0 = ashalf2(qa.x), q1 = ashalf2(qa.y), q2 = ashalf2(qa.z), q3 = ashalf2(qa.w);
    half2v q4 = ashalf2(qc.x), q5 = ashalf2(qc.y), q6 = ashalf2(qc.z), q7 = ashalf2(qc.w);

    float d = 0.f;
    float a0 = 0.f, a1 = 0.f, a2 = 0.f, a3 = 0.f, a4 = 0.f, a5 = 0.f, a6 = 0.f, a7 = 0.f;

    for (int c0 = beg; c0 < end; c0 += 64) {
        int cnt = min(64, end - c0);

        // ---- phase 1: alpha / w ----
        int nit = (cnt + 7) >> 3;
        for (int it = 0; it < nit; it++) {
            int idx = it * 8 + slot;
            bool val = idx < cnt;
            int gi = c0 + (val ? idx : 0);
            int2 pe = epair[gi];
            int s = pe.y;
            const unsigned short* kp = Kh + (size_t)s * F + h * 16;
            uint4 ka = *(const uint4*)(kp);
            uint4 kc = *(const uint4*)(kp + 8);
            float p0 = 0.f, p1 = 0.f;
            p0 = FDOT2(q0, ashalf2(ka.x), p0);
            p0 = FDOT2(q1, ashalf2(ka.y), p0);
            p0 = FDOT2(q2, ashalf2(ka.z), p0);
            p0 = FDOT2(q3, ashalf2(ka.w), p0);
            p1 = FDOT2(q4, ashalf2(kc.x), p1);
            p1 = FDOT2(q5, ashalf2(kc.y), p1);
            p1 = FDOT2(q6, ashalf2(kc.z), p1);
            p1 = FDOT2(q7, ashalf2(kc.w), p1);
            float w = __expf((p0 + p1) * 0.25f);  // 1/sqrt(16)
            if (!val) w = 0.f;
            d += w;
            wbuf[wv][idx][h] = w;
            if (h == 0) { sbuf[wv][idx] = s; ebuf[wv][idx] = pe.x; }
            if (multi && val) aout[(size_t)pe.x * HEADS + h] = w;  // rare fallback
        }

        // ---- phase 2: V accumulation ----
        for (int j = 0; j < cnt; j += 8) {
            int idx0 = j + g;
            int idx1 = j + 4 + g;
            bool v0 = idx0 < cnt;
            bool v1 = idx1 < cnt;
            int s0 = sbuf[wv][v0 ? idx0 : 0];
            int s1 = sbuf[wv][v1 ? idx1 : 0];
            float w0 = wbuf[wv][v0 ? idx0 : 0][fh];
            float w1 = wbuf[wv][v1 ? idx1 : 0][fh];
            if (!v0) w0 = 0.f;
            if (!v1) w1 = 0.f;
            uint4 va = *(const uint4*)&Vh[(size_t)s0 * F + fl * 8];
            uint4 vb2 = *(const uint4*)&Vh[(size_t)s1 * F + fl * 8];
            half2v x0 = ashalf2(va.x), x1 = ashalf2(va.y), x2 = ashalf2(va.z), x3 = ashalf2(va.w);
            half2v y0 = ashalf2(vb2.x), y1 = ashalf2(vb2.y), y2 = ashalf2(vb2.z), y3 = ashalf2(vb2.w);
            a0 += w0 * (float)x0[0]; a1 += w0 * (float)x0[1];
            a2 += w0 * (float)x1[0]; a3 += w0 * (float)x1[1];
            a4 += w0 * (float)x2[0]; a5 += w0 * (float)x2[1];
            a6 += w0 * (float)x3[0]; a7 += w0 * (float)x3[1];
            a0 += w1 * (float)y0[0]; a1 += w1 * (float)y0[1];
            a2 += w1 * (float)y1[0]; a3 += w1 * (float)y1[1];
            a4 += w1 * (float)y2[0]; a5 += w1 * (float)y2[1];
            a6 += w1 * (float)y3[0]; a7 += w1 * (float)y3[1];
        }
    }

    // reduce d over slots (lanes sharing h)
    d += __shfl_xor(d, 8);
    d += __shfl_xor(d, 16);
    d += __shfl_xor(d, 32);
    float inv_d = (d > 0.f) ? 1.f / d : 0.f;
    if (slot == 0) mdbuf[wv][h] = inv_d;

    // ---- fused alpha normalization (reads wbuf w's before they're clobbered) ----
    if (!multi) {
        for (int idx = slot; idx < deg; idx += 8)
            aout[(size_t)ebuf[wv][idx] * HEADS + h] = wbuf[wv][idx][h] * inv_d;
    } else {
        for (int idx = slot; idx < deg; idx += 8)
            aout[(size_t)epair[beg + idx].x * HEADS + h] *= inv_d;
    }

    // ---- epilogue spread over all 64 lanes ----
    // dump group partials: wbuf[wv][lane][r] = a_r  (row = g*16 + fl)
    *(float4*)&wbuf[wv][lane][0] = make_float4(a0, a1, a2, a3);
    *(float4*)&wbuf[wv][lane][4] = make_float4(a4, a5, a6, a7);
    asm volatile("s_waitcnt lgkmcnt(0)" ::: "memory");

    // each lane owns features f0 = lane*2, f0+1
    int f0 = lane * 2;
    int frow = f0 >> 3;          // = lane>>2
    int fcol = f0 & 7;           // even
    float t0 = 0.f, t1 = 0.f;
#pragma unroll
    for (int gg = 0; gg < 4; gg++) {
        float2 pr = *(const float2*)&wbuf[wv][gg * 16 + frow][fcol];
        t0 += pr.x; t1 += pr.y;
    }
    float invd = mdbuf[wv][lane >> 3];   // head = f0/16
    float2 sv = *(const float2*)&S[(size_t)n * F + f0];
    float o0 = t0 * invd + sv.x;
    float o1 = t1 * invd + sv.y;
    if (do_gelu) {
        o0 = gelu_exact(o0);
        o1 = gelu_exact(o1);
        unsigned ob = (unsigned)f2bf(o0) | ((unsigned)f2bf(o1) << 16);
        *(unsigned*)&hout_b[(size_t)n * F + f0] = ob;
    } else {
        *(float2*)&hout_f[(size_t)n * F + f0] = make_float2(o0, o1);
    }
}

// ---------------- launch ----------------

extern "C" void kernel_launch(void* const* d_in, const int* in_sizes, int n_in,
                              void* d_out, int out_size, void* d_ws, size_t ws_size,
                              hipStream_t stream) {
    const float* x  = (const float*)d_in[0];
    const int*   ei = (const int*)d_in[1];
    const float* Wq = (const float*)d_in[2];
    const float* bq = (const float*)d_in[3];
    const float* Wk = (const float*)d_in[4];
    const float* bk = (const float*)d_in[5];
    const float* Wv = (const float*)d_in[6];
    const float* bv = (const float*)d_in[7];
    const float* Ws = (const float*)d_in[8];
    const float* bs = (const float*)d_in[9];

    const int N = in_sizes[0] / F;
    const int E = in_sizes[1] / 2;
    const int L = in_sizes[2] / (F * F);

    // workspace layout
    float* Sb = (float*)d_ws;                             // N*F fp32
    unsigned short* Qh = (unsigned short*)(Sb + (size_t)N * F);  // N*F f16
    unsigned short* xb = Qh + (size_t)N * F;              // N*F bf16
    unsigned short* hb = xb + (size_t)N * F;              // N*F bf16
    unsigned short* Kb = hb + (size_t)N * F;              // N*F f16
    unsigned short* Vb = Kb + (size_t)N * F;              // N*F f16
    unsigned short* wfrag = Vb + (size_t)N * F;           // L*4*16384 bf16
    int2* epair = (int2*)(wfrag + (size_t)L * 4 * 16384); // E int2 (8B aligned)
    int* start = (int*)(epair + E);                       // N+1
    int* cursor = start + (N + 1);                        // N
    int* partials = cursor + N;                           // <=256

    float* out_h = (float*)d_out;                         // N*F
    float* out_a = out_h + (size_t)N * F;                 // L*E*HEADS

    const int* srcIdx = ei;
    const int* dstIdx = ei + E;

    int nbScan = (N + 255) / 256;
    hipMemsetAsync(cursor, 0, sizeof(int) * N, stream);
    hist_k<<<(E + 255) / 256, 256, 0, stream>>>(dstIdx, E, cursor);
    scan1_k<<<nbScan, 256, 0, stream>>>(cursor, N, start, partials);
    scan2_k<<<1, 256, 0, stream>>>(partials, nbScan, start, N, E);
    scan3_k<<<nbScan, 256, 0, stream>>>(start, N, partials);
    hipMemsetAsync(cursor, 0, sizeof(int) * N, stream);
    fill_k<<<(E + 255) / 256, 256, 0, stream>>>(srcIdx, dstIdx, E, start, cursor, epair);

    int wtotal = L * 4 * 16384;
    wprep_k<<<(wtotal + 255) / 256, 256, 0, stream>>>(Wq, Wk, Wv, Ws, wfrag, wtotal);
    cvt_k<<<((N * F / 4) + 255) / 256, 256, 0, stream>>>(x, xb, N * F / 4);

    for (int l = 0; l < L; ++l) {
        const unsigned short* hin = (l == 0) ? xb : hb;
        gemm_mfma<<<(N + 31) / 32, 256, 0, stream>>>(
            hin, wfrag + (size_t)l * 4 * 16384,
            bq + (size_t)l * F, bk + (size_t)l * F,
            bv + (size_t)l * F, bs + (size_t)l * F,
            Qh, Kb, Vb, Sb, N);
        edge_k<<<(N + 3) / 4, 256, 0, stream>>>(
            Qh, Kb, Vb, Sb, start, epair,
            out_a + (size_t)l * E * HEADS, out_h, hb, N, (l < L - 1) ? 1 : 0);
    }
}

// Round 5
// 668.124 us; speedup vs baseline: 1.0534x; 1.0172x over previous
//
#include <hip/hip_runtime.h>
#include <math.h>

#define F 128
#define HEADS 8

typedef __attribute__((ext_vector_type(8))) short short8;
typedef __attribute__((ext_vector_type(4))) float floatx4;
typedef __attribute__((ext_vector_type(2))) _Float16 half2v;

__device__ __forceinline__ unsigned short f2bf(float f) {
    unsigned u = __float_as_uint(f);
    unsigned r = u + 0x7FFFu + ((u >> 16) & 1u);
    return (unsigned short)(r >> 16);
}

__device__ __forceinline__ half2v ashalf2(unsigned u) {
    return __builtin_bit_cast(half2v, u);
}
__device__ __forceinline__ unsigned pkh(float a, float b) {
    return __builtin_bit_cast(unsigned, __builtin_amdgcn_cvt_pkrtz(a, b));
}

#if __has_builtin(__builtin_amdgcn_fdot2)
#define FDOT2(a, b, c) __builtin_amdgcn_fdot2((a), (b), (c), false)
#else
#define FDOT2(a, b, c) ((c) + (float)(a)[0] * (float)(b)[0] + (float)(a)[1] * (float)(b)[1])
#endif

// ---------------- fused setup: x->bf16 cvt + weight pre-swizzle + zero deg/cursor ----------------
// one dispatch replaces cvt_k, wprep_k and two hipMemsetAsync.

__global__ __launch_bounds__(256) void setup_k(
    const float* __restrict__ x, unsigned short* __restrict__ xb, int total4,
    const float* __restrict__ Wq, const float* __restrict__ Wk,
    const float* __restrict__ Wv, const float* __restrict__ Ws,
    unsigned short* __restrict__ wfrag, int wtotal,
    int* __restrict__ deg, int* __restrict__ cursor, int N) {
    int idx = blockIdx.x * 256 + threadIdx.x;
    if (idx < total4) {
        float4 v = ((const float4*)x)[idx];
        ushort4 o;
        o.x = f2bf(v.x); o.y = f2bf(v.y); o.z = f2bf(v.z); o.w = f2bf(v.w);
        ((ushort4*)xb)[idx] = o;
        return;
    }
    idx -= total4;
    if (idx < wtotal) {
        int j = idx & 7;
        int lane = (idx >> 3) & 63;
        int rest = idx >> 9;
        int chunk = rest & 3;
        int ftile = (rest >> 2) & 7;
        int mat = (rest >> 5) & 3;
        int layer = rest >> 7;
        int k = chunk * 32 + (lane >> 4) * 8 + j;
        int f = ftile * 16 + (lane & 15);
        const float* W = (mat == 0) ? Wq : (mat == 1) ? Wk : (mat == 2) ? Wv : Ws;
        wfrag[idx] = f2bf(W[((size_t)layer * F + k) * F + f]);
        return;
    }
    idx -= wtotal;
    if (idx < N) deg[idx] = 0;
    else if (idx < 2 * N) cursor[idx - N] = 0;
}

// ---------------- CSR build ----------------

__global__ __launch_bounds__(256) void hist_k(const int* __restrict__ dst, int E, int* __restrict__ deg) {
    int e = blockIdx.x * 256 + threadIdx.x;
    if (e < E) atomicAdd(&deg[dst[e]], 1);
}

__global__ __launch_bounds__(256) void scan1_k(const int* __restrict__ deg, int N,
                                               int* __restrict__ start, int* __restrict__ partials) {
    __shared__ int sm[256];
    int t = threadIdx.x;
    int i = blockIdx.x * 256 + t;
    int v = (i < N) ? deg[i] : 0;
    sm[t] = v;
    __syncthreads();
    for (int off = 1; off < 256; off <<= 1) {
        int add = (t >= off) ? sm[t - off] : 0;
        __syncthreads();
        sm[t] += add;
        __syncthreads();
    }
    if (i < N) start[i] = sm[t] - v;
    if (t == 255) partials[blockIdx.x] = sm[t];
}

// scan of block partials + apply to start[] in one single-block dispatch
__global__ __launch_bounds__(256) void scan23_k(const int* __restrict__ partials, int nb,
                                                int* __restrict__ start, int N, int E) {
    __shared__ int sm[256];
    int t = threadIdx.x;
    int v = (t < nb) ? partials[t] : 0;
    sm[t] = v;
    __syncthreads();
    for (int off = 1; off < 256; off <<= 1) {
        int add = (t >= off) ? sm[t - off] : 0;
        __syncthreads();
        sm[t] += add;
        __syncthreads();
    }
    int myoff = sm[t] - v;       // exclusive block offset
    __syncthreads();
    sm[t] = myoff;
    __syncthreads();
    for (int i = t; i < N; i += 256) start[i] += sm[i >> 8];
    if (t == 0) start[N] = E;
}

// epair[i] = (edge_id, src)
__global__ __launch_bounds__(256) void fill_k(const int* __restrict__ src, const int* __restrict__ dst, int E,
                                              const int* __restrict__ start, int* __restrict__ cursor,
                                              int2* __restrict__ epair) {
    int e = blockIdx.x * 256 + threadIdx.x;
    if (e < E) {
        int dd = dst[e];
        int pos = atomicAdd(&cursor[dd], 1);
        epair[start[dd] + pos] = make_int2(e, src[e]);
    }
}

// ---------------- fused QKVS GEMM via bf16 MFMA ----------------
// wave 0:Q 1:K 2:V 3:S, all f16 outputs, 32 nodes per block.

__global__ __launch_bounds__(256) void gemm_mfma(
    const unsigned short* __restrict__ xb, const unsigned short* __restrict__ wfrag,
    const float* __restrict__ bq, const float* __restrict__ bk,
    const float* __restrict__ bv, const float* __restrict__ bs,
    unsigned short* __restrict__ Qh, unsigned short* __restrict__ Kh,
    unsigned short* __restrict__ Vh, unsigned short* __restrict__ Sh, int N) {
    int wave = threadIdx.x >> 6;
    int lane = threadIdx.x & 63;
    int row0 = blockIdx.x * 32;
    int lm = lane & 15, quad = lane >> 4;
    const unsigned short* wf = wfrag + wave * 16384;

    floatx4 acc[2][8];
#pragma unroll
    for (int t = 0; t < 2; t++)
#pragma unroll
        for (int u = 0; u < 8; u++) acc[t][u] = (floatx4){0.f, 0.f, 0.f, 0.f};

#pragma unroll
    for (int chunk = 0; chunk < 4; chunk++) {
        short8 xfr[2];
#pragma unroll
        for (int t = 0; t < 2; t++) {
            int m = row0 + t * 16 + lm;
            m = (m < N) ? m : (N - 1);
            xfr[t] = *(const short8*)(xb + (size_t)m * F + chunk * 32 + quad * 8);
        }
#pragma unroll
        for (int u = 0; u < 8; u++) {
            short8 wfr = *(const short8*)(wf + ((u * 4 + chunk) * 64 + lane) * 8);
            acc[0][u] = __builtin_amdgcn_mfma_f32_16x16x32_bf16(wfr, xfr[0], acc[0][u], 0, 0, 0);
            acc[1][u] = __builtin_amdgcn_mfma_f32_16x16x32_bf16(wfr, xfr[1], acc[1][u], 0, 0, 0);
        }
    }

    const float* bias = (wave == 0) ? bq : (wave == 1) ? bk : (wave == 2) ? bv : bs;
    unsigned short* dp = (wave == 0) ? Qh : (wave == 1) ? Kh : (wave == 2) ? Vh : Sh;
#pragma unroll
    for (int u = 0; u < 8; u++) {
        float4 bv4 = *(const float4*)&bias[u * 16 + quad * 4];
#pragma unroll
        for (int t = 0; t < 2; t++) {
            int node = row0 + t * 16 + lm;
            if (node < N) {
                floatx4 a = acc[t][u];
                size_t off = (size_t)node * F + u * 16 + quad * 4;
                *(uint2*)&dp[off] = make_uint2(pkh(a[0] + bv4.x, a[1] + bv4.y),
                                               pkh(a[2] + bv4.z, a[3] + bv4.w));
            }
        }
    }
}

// ---------------- fused edge kernel: one wave per destination node ----------------
// Chunk start: one coalesced epair load -> LDS (byte offsets + eids).
// Phase 1: lane=(slot,h): 16-dim f16 dot via v_dot2, src offset via LDS broadcast.
// Phase 2: lane=(g,fl): V rows f16 16B/lane, 32-bit byte-offset addressing.
// Epilogue: partials through LDS, all 64 lanes do S-add + gelu (2 features each).

__device__ __forceinline__ float gelu_exact(float v) {
    return 0.5f * v * (1.0f + erff(v * 0.70710678118654752f));
}

__global__ __launch_bounds__(256) void edge_k(
    const unsigned short* __restrict__ Qh, const unsigned short* __restrict__ Kh,
    const unsigned short* __restrict__ Vh, const unsigned short* __restrict__ Sh,
    const int* __restrict__ start, const int2* __restrict__ epair,
    float* __restrict__ aout,
    float* __restrict__ hout_f, unsigned short* __restrict__ hout_b,
    int N, int do_gelu) {
    __shared__ float wbuf[4][64][8];   // w values; reused for output partials
    __shared__ int sbuf[4][64];        // src byte offsets (src * 256)
    __shared__ int ebuf[4][64];        // edge ids
    __shared__ float mdbuf[4][8];

    int wv = threadIdx.x >> 6;
    int lane = threadIdx.x & 63;
    int n = blockIdx.x * 4 + wv;
    if (n >= N) return;   // no block-level barriers below: safe

    int beg = start[n], end = start[n + 1];
    int deg = end - beg;
    bool multi = deg > 64;
    int slot = lane >> 3, h = lane & 7;
    int g = lane >> 4, fl = lane & 15;
    int fh = fl >> 1;

    // q for head h: 16 f16
    const unsigned short* qp = Qh + (size_t)n * F + h * 16;
    uint4 qa = *(const uint4*)(qp);
    uint4 qc = *(const uint4*)(qp + 8);
    half2v q0 = ashalf2(qa.x), q1 = ashalf2(qa.y), q2 = ashalf2(qa.z), q3 = ashalf2(qa.w);
    half2v q4 = ashalf2(qc.x), q5 = ashalf2(qc.y), q6 = ashalf2(qc.z), q7 = ashalf2(qc.w);

    float d = 0.f;
    float a0 = 0.f, a1 = 0.f, a2 = 0.f, a3 = 0.f, a4 = 0.f, a5 = 0.f, a6 = 0.f, a7 = 0.f;

    for (int c0 = beg; c0 < end; c0 += 64) {
        int cnt = min(64, end - c0);

        // one coalesced load covers the chunk; distribute through LDS
        int2 pe = epair[c0 + min(lane, cnt - 1)];
        sbuf[wv][lane] = pe.y << 8;     // src * F * sizeof(f16)
        ebuf[wv][lane] = pe.x;

        // ---- phase 1: alpha / w ----
        int nit = (cnt + 7) >> 3;
        for (int it = 0; it < nit; it++) {
            int idx = it * 8 + slot;
            bool val = idx < cnt;
            int ofs = sbuf[wv][val ? idx : 0];   // LDS broadcast (8 lanes same addr)
            const unsigned short* kp = (const unsigned short*)((const char*)Kh + ofs) + h * 16;
            uint4 ka = *(const uint4*)(kp);
            uint4 kc = *(const uint4*)(kp + 8);
            float p0 = 0.f, p1 = 0.f;
            p0 = FDOT2(q0, ashalf2(ka.x), p0);
            p0 = FDOT2(q1, ashalf2(ka.y), p0);
            p0 = FDOT2(q2, ashalf2(ka.z), p0);
            p0 = FDOT2(q3, ashalf2(ka.w), p0);
            p1 = FDOT2(q4, ashalf2(kc.x), p1);
            p1 = FDOT2(q5, ashalf2(kc.y), p1);
            p1 = FDOT2(q6, ashalf2(kc.z), p1);
            p1 = FDOT2(q7, ashalf2(kc.w), p1);
            float w = __expf((p0 + p1) * 0.25f);  // 1/sqrt(16)
            if (!val) w = 0.f;
            d += w;
            wbuf[wv][idx][h] = w;
            if (multi && val) aout[(size_t)ebuf[wv][idx] * HEADS + h] = w;  // rare fallback
        }

        // ---- phase 2: V accumulation ----
        for (int j = 0; j < cnt; j += 8) {
            int idx0 = j + g;
            int idx1 = j + 4 + g;
            bool v0 = idx0 < cnt;
            bool v1 = idx1 < cnt;
            int o0s = sbuf[wv][v0 ? idx0 : 0];
            int o1s = sbuf[wv][v1 ? idx1 : 0];
            float w0 = wbuf[wv][v0 ? idx0 : 0][fh];
            float w1 = wbuf[wv][v1 ? idx1 : 0][fh];
            if (!v0) w0 = 0.f;
            if (!v1) w1 = 0.f;
            uint4 va = *(const uint4*)((const char*)Vh + o0s + fl * 16);
            uint4 vb2 = *(const uint4*)((const char*)Vh + o1s + fl * 16);
            half2v x0 = ashalf2(va.x), x1 = ashalf2(va.y), x2 = ashalf2(va.z), x3 = ashalf2(va.w);
            half2v y0 = ashalf2(vb2.x), y1 = ashalf2(vb2.y), y2 = ashalf2(vb2.z), y3 = ashalf2(vb2.w);
            a0 += w0 * (float)x0[0]; a1 += w0 * (float)x0[1];
            a2 += w0 * (float)x1[0]; a3 += w0 * (float)x1[1];
            a4 += w0 * (float)x2[0]; a5 += w0 * (float)x2[1];
            a6 += w0 * (float)x3[0]; a7 += w0 * (float)x3[1];
            a0 += w1 * (float)y0[0]; a1 += w1 * (float)y0[1];
            a2 += w1 * (float)y1[0]; a3 += w1 * (float)y1[1];
            a4 += w1 * (float)y2[0]; a5 += w1 * (float)y2[1];
            a6 += w1 * (float)y3[0]; a7 += w1 * (float)y3[1];
        }
    }

    // reduce d over slots (lanes sharing h)
    d += __shfl_xor(d, 8);
    d += __shfl_xor(d, 16);
    d += __shfl_xor(d, 32);
    float inv_d = (d > 0.f) ? 1.f / d : 0.f;
    if (slot == 0) mdbuf[wv][h] = inv_d;

    // ---- fused alpha normalization (reads wbuf/ebuf of the last=only chunk) ----
    if (!multi) {
        for (int idx = slot; idx < deg; idx += 8)
            aout[(size_t)ebuf[wv][idx] * HEADS + h] = wbuf[wv][idx][h] * inv_d;
    } else {
        for (int idx = slot; idx < deg; idx += 8)
            aout[(size_t)epair[beg + idx].x * HEADS + h] *= inv_d;
    }

    // ---- epilogue spread over all 64 lanes ----
    *(float4*)&wbuf[wv][lane][0] = make_float4(a0, a1, a2, a3);
    *(float4*)&wbuf[wv][lane][4] = make_float4(a4, a5, a6, a7);
    asm volatile("s_waitcnt lgkmcnt(0)" ::: "memory");

    // each lane owns features f0 = lane*2, f0+1
    int f0 = lane * 2;
    int frow = f0 >> 3;
    int fcol = f0 & 7;
    float t0 = 0.f, t1 = 0.f;
#pragma unroll
    for (int gg = 0; gg < 4; gg++) {
        float2 pr = *(const float2*)&wbuf[wv][gg * 16 + frow][fcol];
        t0 += pr.x; t1 += pr.y;
    }
    float invd = mdbuf[wv][lane >> 3];
    half2v s2 = ashalf2(*(const unsigned*)&Sh[(size_t)n * F + f0]);
    float o0 = t0 * invd + (float)s2[0];
    float o1 = t1 * invd + (float)s2[1];
    if (do_gelu) {
        o0 = gelu_exact(o0);
        o1 = gelu_exact(o1);
        unsigned ob = (unsigned)f2bf(o0) | ((unsigned)f2bf(o1) << 16);
        *(unsigned*)&hout_b[(size_t)n * F + f0] = ob;
    } else {
        *(float2*)&hout_f[(size_t)n * F + f0] = make_float2(o0, o1);
    }
}

// ---------------- launch ----------------

extern "C" void kernel_launch(void* const* d_in, const int* in_sizes, int n_in,
                              void* d_out, int out_size, void* d_ws, size_t ws_size,
                              hipStream_t stream) {
    const float* x  = (const float*)d_in[0];
    const int*   ei = (const int*)d_in[1];
    const float* Wq = (const float*)d_in[2];
    const float* bq = (const float*)d_in[3];
    const float* Wk = (const float*)d_in[4];
    const float* bk = (const float*)d_in[5];
    const float* Wv = (const float*)d_in[6];
    const float* bv = (const float*)d_in[7];
    const float* Ws = (const float*)d_in[8];
    const float* bs = (const float*)d_in[9];

    const int N = in_sizes[0] / F;
    const int E = in_sizes[1] / 2;
    const int L = in_sizes[2] / (F * F);

    // workspace layout (all f16 node tensors)
    unsigned short* Sh = (unsigned short*)d_ws;           // N*F f16
    unsigned short* Qh = Sh + (size_t)N * F;              // N*F f16
    unsigned short* xb = Qh + (size_t)N * F;              // N*F bf16
    unsigned short* hb = xb + (size_t)N * F;              // N*F bf16
    unsigned short* Kb = hb + (size_t)N * F;              // N*F f16
    unsigned short* Vb = Kb + (size_t)N * F;              // N*F f16
    unsigned short* wfrag = Vb + (size_t)N * F;           // L*4*16384 bf16
    int2* epair = (int2*)(wfrag + (size_t)L * 4 * 16384); // E int2
    int* start = (int*)(epair + E);                       // N+1
    int* cursor = start + (N + 1);                        // N
    int* deg = cursor + N;                                // N
    int* partials = deg + N;                              // <=256

    float* out_h = (float*)d_out;                         // N*F
    float* out_a = out_h + (size_t)N * F;                 // L*E*HEADS

    const int* srcIdx = ei;
    const int* dstIdx = ei + E;

    int total4 = N * F / 4;
    int wtotal = L * 4 * 16384;
    int stotal = total4 + wtotal + 2 * N;
    setup_k<<<(stotal + 255) / 256, 256, 0, stream>>>(
        x, xb, total4, Wq, Wk, Wv, Ws, wfrag, wtotal, deg, cursor, N);

    int nbScan = (N + 255) / 256;
    hist_k<<<(E + 255) / 256, 256, 0, stream>>>(dstIdx, E, deg);
    scan1_k<<<nbScan, 256, 0, stream>>>(deg, N, start, partials);
    scan23_k<<<1, 256, 0, stream>>>(partials, nbScan, start, N, E);
    fill_k<<<(E + 255) / 256, 256, 0, stream>>>(srcIdx, dstIdx, E, start, cursor, epair);

    for (int l = 0; l < L; ++l) {
        const unsigned short* hin = (l == 0) ? xb : hb;
        gemm_mfma<<<(N + 31) / 32, 256, 0, stream>>>(
            hin, wfrag + (size_t)l * 4 * 16384,
            bq + (size_t)l * F, bk + (size_t)l * F,
            bv + (size_t)l * F, bs + (size_t)l * F,
            Qh, Kb, Vb, Sh, N);
        edge_k<<<(N + 3) / 4, 256, 0, stream>>>(
            Qh, Kb, Vb, Sh, start, epair,
            out_a + (size_t)l * E * HEADS, out_h, hb, N, (l < L - 1) ? 1 : 0);
    }
}